// Round 1
// baseline (103.396 us; speedup 1.0000x reference)
//
#include <hip/hip_runtime.h>
#include <hip/hip_bf16.h>

typedef __attribute__((ext_vector_type(8))) short bf16x8;
typedef __attribute__((ext_vector_type(4))) float f32x4;

#define CIN   128
#define COUT  256
#define NIMG  32
#define HWDIM 56
#define HPAD  58
#define KTOT  1152            // 9*128
#define HWIMG 3136            // 56*56
#define MTOT  100352          // 32*3136
#define BS    128             // spatial tile (GEMM N)
#define BF    128             // cout tile   (GEMM M)
#define BK    64

__device__ __forceinline__ void gload16(const void* g, void* l) {
  __builtin_amdgcn_global_load_lds((const __attribute__((address_space(1))) void*)g,
                                   (__attribute__((address_space(3))) void*)l,
                                   16, 0, 0);
}

// ---------------- pre-pass 0: zero workspace (xp region incl. halo) -------
__global__ __launch_bounds__(256)
void zero_xp(float4* __restrict__ p, int n16) {
  int i = blockIdx.x * 256 + threadIdx.x;
  int stride = gridDim.x * 256;
  float4 z; z.x = 0.f; z.y = 0.f; z.z = 0.f; z.w = 0.f;
  for (; i < n16; i += stride) p[i] = z;
}

// ---------------- pre-pass 1: x NCHW f32 -> padded NHWC bf16 --------------
// xp[n][h+1][w+1][c] = bf16(x[n][c][h][w]); borders stay zero.
__global__ __launch_bounds__(256)
void prep_x(const float* __restrict__ x, __hip_bfloat16* __restrict__ xp) {
  __shared__ float tile[CIN * 57];   // padded stride 57 -> conflict-free transpose
  const int nh = blockIdx.x;         // 0 .. 32*56-1
  const int n = nh / HWDIM;
  const int h = nh - n * HWDIM;
  const int t = threadIdx.x;

  const float* src = x + (size_t)n * CIN * HWIMG + (size_t)h * HWDIM;
  for (int i = t; i < CIN * HWDIM; i += 256) {
    int c = i / HWDIM;
    int w = i - c * HWDIM;
    tile[c * 57 + w] = src[(size_t)c * HWIMG + w];
  }
  __syncthreads();

  __hip_bfloat16* dst = xp + (((size_t)n * HPAD + (h + 1)) * HPAD + 1) * CIN;
  for (int o = t; o < HWDIM * 64; o += 256) {   // pairs of channels
    int w = o >> 6;
    int c = (o & 63) * 2;
    __hip_bfloat162 pr;
    pr.x = __float2bfloat16(tile[c * 57 + w]);
    pr.y = __float2bfloat16(tile[(c + 1) * 57 + w]);
    *reinterpret_cast<__hip_bfloat162*>(dst + (size_t)w * CIN + c) = pr;
  }
}

// ---------------- pre-pass 2: weights -> sign, bf16, [cout][tap][cin] -----
__global__ __launch_bounds__(256)
void prep_w(const float* __restrict__ wsrc, __hip_bfloat16* __restrict__ wt) {
  int o = blockIdx.x * 256 + threadIdx.x;
  if (o >= COUT * KTOT) return;
  int cout = o / KTOT;
  int r = o - cout * KTOT;
  int tap = r >> 7;          // 0..8
  int cin = r & 127;
  float v = wsrc[((size_t)cout * CIN + cin) * 9 + tap];
  float s = (v > 0.f) ? 1.f : ((v < 0.f) ? -1.f : 0.f);
  wt[o] = __float2bfloat16(s);
}

// ---------------- main: implicit-GEMM binary conv, bf16 MFMA --------------
// GEMM: D[cout][m] = sum_k W[cout][k] * X[k][m], k = (tap, cin)
// A tile (weights) LDS [128 cout][64 k], B tile (x) LDS [128 m][64 k],
// both XOR-swizzled (slot ^= row&7) via pre-swizzled global source.
__global__ __launch_bounds__(256, 2)
void bconv_mfma(const short* __restrict__ xp, const short* __restrict__ wt,
                const float* __restrict__ bias, float* __restrict__ out) {
  __shared__ short lw[BF * BK];   // 16 KB
  __shared__ short lx[BS * BK];   // 16 KB

  const int tid  = threadIdx.x;
  const int lane = tid & 63;
  const int wv   = tid >> 6;
  const int wm   = wv >> 1;       // cout half of block
  const int wn   = wv & 1;        // spatial half of block
  const int s0   = blockIdx.x * BS;
  const int f0   = blockIdx.y * BF;

  // staging mapping: 8 threads/row, 32 rows/round, 4 rounds
  const int srow = tid >> 3;      // 0..31
  const int slot = tid & 7;
  const int swz  = slot ^ (srow & 7);

  int xoff[4];
  int woff[4];
#pragma unroll
  for (int r = 0; r < 4; ++r) {
    int m  = s0 + r * 32 + srow;
    int n  = m / HWIMG;
    int hw = m - n * HWIMG;
    int h  = hw / HWDIM;
    int w  = hw - h * HWDIM;
    xoff[r] = ((n * HPAD + h) * HPAD + w) * CIN + swz * 8;   // tap (0,0), cin 0
    woff[r] = (f0 + r * 32 + srow) * KTOT + swz * 8;
  }

  f32x4 acc[4][4] = {};

  short* lwdst = &lw[(wv * 8) * BK];   // wave-uniform LDS bases
  short* lxdst = &lx[(wv * 8) * BK];

  for (int ks = 0; ks < 18; ++ks) {
    const int tap = ks >> 1;
    const int kh  = tap / 3;
    const int kw  = tap - kh * 3;
    const int xko = (kh * HPAD + kw) * CIN + (ks & 1) * BK;
    const int wko = ks * BK;

    __syncthreads();   // previous compute done before overwriting LDS
#pragma unroll
    for (int r = 0; r < 4; ++r) {
      gload16(wt + woff[r] + wko, lwdst + r * 32 * BK);
      gload16(xp + xoff[r] + xko, lxdst + r * 32 * BK);
    }
    __syncthreads();   // drains vmcnt -> tiles ready

#pragma unroll
    for (int ksub = 0; ksub < 2; ++ksub) {
      const int rlo = lane & 15;
      const int sx  = (ksub * 4 + (lane >> 4)) ^ (rlo & 7);
      bf16x8 af[4], bx[4];
#pragma unroll
      for (int f = 0; f < 4; ++f) {
        int row = wm * 64 + f * 16 + rlo;
        af[f] = *(const bf16x8*)&lw[row * BK + sx * 8];
      }
#pragma unroll
      for (int f = 0; f < 4; ++f) {
        int row = wn * 64 + f * 16 + rlo;
        bx[f] = *(const bf16x8*)&lx[row * BK + sx * 8];
      }
#pragma unroll
      for (int fm = 0; fm < 4; ++fm)
#pragma unroll
        for (int fn = 0; fn < 4; ++fn)
          acc[fm][fn] = __builtin_amdgcn_mfma_f32_16x16x32_bf16(
              af[fm], bx[fn], acc[fm][fn], 0, 0, 0);
    }
  }

  // epilogue: D row = cout, col = spatial m (verified m89 C/D layout)
  const int col = lane & 15;
  const int rg  = lane >> 4;
#pragma unroll
  for (int fn = 0; fn < 4; ++fn) {
    int m  = s0 + wn * 64 + fn * 16 + col;
    int n  = m / HWIMG;
    int hw = m - n * HWIMG;
    float* obase = out + (size_t)n * (COUT * HWIMG) + hw;
#pragma unroll
    for (int fm = 0; fm < 4; ++fm) {
      int c0 = f0 + wm * 64 + fm * 16 + rg * 4;
#pragma unroll
      for (int j = 0; j < 4; ++j) {
        int c = c0 + j;
        obase[(size_t)c * HWIMG] = acc[fm][fn][j] + bias[c];
      }
    }
  }
}

extern "C" void kernel_launch(void* const* d_in, const int* in_sizes, int n_in,
                              void* d_out, int out_size, void* d_ws, size_t ws_size,
                              hipStream_t stream) {
  const float* x  = (const float*)d_in[0];
  const float* w  = (const float*)d_in[1];
  const float* b  = (const float*)d_in[2];
  float* out = (float*)d_out;

  const size_t xp_elems = (size_t)NIMG * HPAD * HPAD * CIN;  // 13,774,848 bf16
  __hip_bfloat16* xp = (__hip_bfloat16*)d_ws;
  __hip_bfloat16* wt = xp + xp_elems;

  // 1) zero padded-x region (halo must be 0)
  int n16 = (int)(xp_elems / 8);   // float4 = 8 bf16
  zero_xp<<<2048, 256, 0, stream>>>((float4*)d_ws, n16);

  // 2) x -> padded NHWC bf16
  prep_x<<<NIMG * HWDIM, 256, 0, stream>>>(x, xp);

  // 3) weights -> sign bf16 [cout][tap][cin]
  prep_w<<<(COUT * KTOT + 255) / 256, 256, 0, stream>>>(w, wt);

  // 4) implicit-GEMM MFMA conv
  dim3 grid(MTOT / BS, COUT / BF);
  bconv_mfma<<<grid, 256, 0, stream>>>((const short*)xp, (const short*)wt, b, out);
}